// Round 1
// 765.096 us; speedup vs baseline: 1.0899x; 1.0899x over previous
//
#include <hip/hip_runtime.h>
#include <cstdint>
#include <cmath>

#define N_NODESC 50000
#define N_EDGESC 800000

typedef __bf16 bf16x8 __attribute__((ext_vector_type(8)));
typedef float  f32x4  __attribute__((ext_vector_type(4)));

// ---------------- workspace layout (bytes) ----------------
// QKV    : [0,          38,400,000)   N*192 f32  (Q | K | V per node row)
// counts : [38,400,000, 38,600,000)   N int
// offsets: [38,600,000, 38,800,004)   N+1 int
// cursor : [38,800,004, 39,000,004)   N int
//   ewb  : [38,800,016, 38,832,784)   32 KB prepped bf16 E_weight (hi|lo, swizzled)
//          -- aliases cursor; k_prep writes it before k_edge reads it, and
//          -- k_scan only scribbles cursor AFTER k_edge completes (stream order).
// perm   : [39,000,004, 42,200,004)   E int  (edges sorted by dst)

__global__ __launch_bounds__(256) void k_zero(int* __restrict__ p, int n) {
  int i = blockIdx.x * 256 + threadIdx.x;
  if (i < n) p[i] = 0;
}

// ---------------- prep: E_weight f32 -> split bf16 (hi,lo), XOR-swizzled ----------------
// 1024 threads total: idx -> (j in [0,128), c in [0,8)); 8 consecutive k per chunk.
// Layout byte offset: hi at j*128 + (c^(j&7))*16 ; lo at +16384. Identity-copied to LDS
// by k_edge, so the swizzle is baked into global memory (both-sides rule, m231).
__global__ __launch_bounds__(256) void k_prep(const float* __restrict__ ew,
                                              char* __restrict__ out)
{
  int idx = blockIdx.x * 256 + threadIdx.x;   // [0,1024)
  int j = idx >> 3;
  int c = idx & 7;
  float4 a = *(const float4*)&ew[j * 64 + c * 8];
  float4 b = *(const float4*)&ew[j * 64 + c * 8 + 4];
  float f[8] = {a.x, a.y, a.z, a.w, b.x, b.y, b.z, b.w};
  bf16x8 hv, lv;
#pragma unroll
  for (int i = 0; i < 8; ++i) {
    float fv = f[i];
    __bf16 h = (__bf16)fv;                    // RN to bf16
    hv[i] = h;
    lv[i] = (__bf16)(fv - (float)h);          // residual, RN to bf16
  }
  int swz = c ^ (j & 7);
  *(bf16x8*)(out + j * 128 + swz * 16) = hv;
  *(bf16x8*)(out + 16384 + j * 128 + swz * 16) = lv;
}

// ---------------- QKV = x @ Wqkv^T + b  (N x 192) ----------------
__global__ __launch_bounds__(256) void k_qkv(
    const float* __restrict__ x, const float* __restrict__ w,
    const float* __restrict__ bias, float* __restrict__ qkv, int N)
{
  __shared__ float wT[32 * 193];
  __shared__ float xT[32 * 65];
  const int tid = threadIdx.x;
  const int node0 = blockIdx.x * 64;
  const int tn = tid & 15;
  const int tj = tid >> 4;

  float acc[4][12];
#pragma unroll
  for (int i = 0; i < 4; ++i)
#pragma unroll
    for (int p = 0; p < 12; ++p) acc[i][p] = 0.f;

  for (int kh = 0; kh < 2; ++kh) {
#pragma unroll
    for (int it = 0; it < 6; ++it) {
      int idx4 = tid + it * 256;
      int j = idx4 >> 3;
      int k4 = idx4 & 7;
      float4 a = *(const float4*)&w[j * 64 + kh * 32 + k4 * 4];
      wT[(k4 * 4 + 0) * 193 + j] = a.x;
      wT[(k4 * 4 + 1) * 193 + j] = a.y;
      wT[(k4 * 4 + 2) * 193 + j] = a.z;
      wT[(k4 * 4 + 3) * 193 + j] = a.w;
    }
#pragma unroll
    for (int it = 0; it < 2; ++it) {
      int idx4 = tid + it * 256;
      int n = idx4 >> 3;
      int k4 = idx4 & 7;
      int gn = node0 + n;
      float4 a = make_float4(0.f, 0.f, 0.f, 0.f);
      if (gn < N) a = *(const float4*)&x[gn * 64 + kh * 32 + k4 * 4];
      xT[(k4 * 4 + 0) * 65 + n] = a.x;
      xT[(k4 * 4 + 1) * 65 + n] = a.y;
      xT[(k4 * 4 + 2) * 65 + n] = a.z;
      xT[(k4 * 4 + 3) * 65 + n] = a.w;
    }
    __syncthreads();
#pragma unroll 8
    for (int k = 0; k < 32; ++k) {
      float xa[4], wa[12];
#pragma unroll
      for (int i = 0; i < 4; ++i) xa[i] = xT[k * 65 + tn * 4 + i];
#pragma unroll
      for (int p = 0; p < 12; ++p) wa[p] = wT[k * 193 + tj * 12 + p];
#pragma unroll
      for (int i = 0; i < 4; ++i)
#pragma unroll
        for (int p = 0; p < 12; ++p)
          acc[i][p] = fmaf(xa[i], wa[p], acc[i][p]);
    }
    __syncthreads();
  }

  float b[12];
#pragma unroll
  for (int p = 0; p < 12; ++p) b[p] = bias[tj * 12 + p];
#pragma unroll
  for (int i = 0; i < 4; ++i) {
    int gn = node0 + tn * 4 + i;
    if (gn < N) {
      float* o = &qkv[gn * 192 + tj * 12];
#pragma unroll
      for (int p = 0; p < 12; ++p) o[p] = acc[i][p] + b[p];
    }
  }
}

// ---------------- Edge pass: MFMA split-bf16 GEMM (E x 64) @ (64 x 128) + fused epilogue
// Block: 128 edges, 4 waves x 32 edges (2 A-tiles of 16). K=64 = 2 MFMA steps.
// A (cf) global->reg->hi/lo bf16 fragments (A layout: row=lane&15, k=(lane>>4)*8+i).
// B (E_weight) prepped+swizzled in ws, identity-copied to 32 KB LDS; frag reads are
// ds_read_b128, bank-balanced (8 accesses/bank). 3 MFMAs per (hi*hi + lo*hi + hi*lo).
// D layout (measured, m89/m91): col=lane&15, row=(lane>>4)*4+reg.
__global__ __launch_bounds__(256) void k_edge(
    const float* __restrict__ cf, const int* __restrict__ ei,
    const float* __restrict__ ebias, const char* __restrict__ ewb,
    const float* __restrict__ qkv, float* __restrict__ conn_out,
    int* __restrict__ counts, int E)
{
  __shared__ uint4 Bsh4[2048];              // 32 KB: hi [0,16K), lo [16K,32K)
  char* Bsh = (char*)Bsh4;
  const int tid  = threadIdx.x;
  const int lane = tid & 63;
  const int lr   = lane & 15;               // A row / B col / D col
  const int lg   = lane >> 4;               // k-group
  const int wave = tid >> 6;
  const int e0   = blockIdx.x * 128 + wave * 32;

  // --- issue B copy loads (ws slab is L2-resident after first blocks)
  uint4 breg[8];
#pragma unroll
  for (int it = 0; it < 8; ++it)
    breg[it] = *(const uint4*)(ewb + tid * 16 + it * 4096);

  // --- load A tiles: 2 tiles x 2 K-steps x 8 consecutive f32 per lane
  float af[2][2][8];
#pragma unroll
  for (int t = 0; t < 2; ++t)
#pragma unroll
    for (int s = 0; s < 2; ++s) {
      const float* p = &cf[(size_t)(e0 + t * 16 + lr) * 64 + s * 32 + lg * 8];
      float4 x0 = *(const float4*)p;
      float4 x1 = *(const float4*)(p + 4);
      af[t][s][0] = x0.x; af[t][s][1] = x0.y; af[t][s][2] = x0.z; af[t][s][3] = x0.w;
      af[t][s][4] = x1.x; af[t][s][5] = x1.y; af[t][s][6] = x1.z; af[t][s][7] = x1.w;
    }

  // --- B regs -> LDS (identity copy; consecutive lanes 16B apart: conflict-free)
#pragma unroll
  for (int it = 0; it < 8; ++it)
    *(uint4*)(Bsh + tid * 16 + it * 4096) = breg[it];

  // --- convert A to hi/lo bf16 fragments (overlaps with ds_writes)
  bf16x8 ah[2][2], al[2][2];
#pragma unroll
  for (int t = 0; t < 2; ++t)
#pragma unroll
    for (int s = 0; s < 2; ++s)
#pragma unroll
      for (int i = 0; i < 8; ++i) {
        float fv = af[t][s][i];
        __bf16 h = (__bf16)fv;
        ah[t][s][i] = h;
        al[t][s][i] = (__bf16)(fv - (float)h);
      }

  __syncthreads();

  f32x4 acc[2][8];
#pragma unroll
  for (int t = 0; t < 2; ++t)
#pragma unroll
    for (int ct = 0; ct < 8; ++ct)
      acc[t][ct] = (f32x4){0.f, 0.f, 0.f, 0.f};

  // --- MFMA main: per (s,ct): 2 ds_read_b128, 6 MFMAs (reused over 2 A-tiles)
#pragma unroll
  for (int s = 0; s < 2; ++s) {
    const int swz = ((s * 4 + lg) ^ (lr & 7)) * 16;   // (j&7)==(lr&7) since ct*16%8==0
#pragma unroll
    for (int ct = 0; ct < 8; ++ct) {
      const int j = ct * 16 + lr;
      const bf16x8 bh = *(const bf16x8*)(Bsh + j * 128 + swz);
      const bf16x8 bl = *(const bf16x8*)(Bsh + 16384 + j * 128 + swz);
#pragma unroll
      for (int t = 0; t < 2; ++t) {
        acc[t][ct] = __builtin_amdgcn_mfma_f32_16x16x32_bf16(ah[t][s], bh, acc[t][ct], 0, 0, 0);
        acc[t][ct] = __builtin_amdgcn_mfma_f32_16x16x32_bf16(al[t][s], bh, acc[t][ct], 0, 0, 0);
        acc[t][ct] = __builtin_amdgcn_mfma_f32_16x16x32_bf16(ah[t][s], bl, acc[t][ct], 0, 0, 0);
      }
    }
  }

  // --- fused epilogue: conn = relu(sign_sqrt((Q[dst]+K[src])*Ew) + Eb)
  float be[4], bb[4];
#pragma unroll
  for (int ct = 0; ct < 4; ++ct) {
    be[ct] = ebias[ct * 16 + lr];
    bb[ct] = ebias[64 + ct * 16 + lr];
  }

#pragma unroll
  for (int t = 0; t < 2; ++t) {
#pragma unroll
    for (int r = 0; r < 4; ++r) {
      const int e   = e0 + t * 16 + lg * 4 + r;       // D row -> edge
      const int dst = ei[e];
      const int src = ei[E + e];
      const float* qrow = &qkv[(size_t)dst * 192];
      const float* krow = &qkv[(size_t)src * 192 + 64];
      float* orow = &conn_out[(size_t)e * 64];
#pragma unroll
      for (int ct = 0; ct < 4; ++ct) {
        const int j = ct * 16 + lr;                   // D col
        float aE = acc[t][ct][r]     + be[ct];
        float aB = acc[t][ct + 4][r] + bb[ct];
        float sv = (qrow[j] + krow[j]) * aE;
        float rt = sqrtf(fabsf(sv));
        float c2 = (sv >= 0.f) ? rt : -rt;            // sqrt_relu(x)-sqrt_relu(-x)
        orow[j] = fmaxf(c2 + aB, 0.f);
      }
      if (lr == 0) atomicAdd(&counts[dst], 1);
    }
  }
}

// ---------------- single-block exclusive scan (CSR offsets + cursor) ----------------
__global__ void k_scan(const int* __restrict__ counts, int* __restrict__ offsets,
                       int* __restrict__ cursor, int n)
{
  __shared__ int sh[1024];
  const int tid = threadIdx.x;
  const int per = (n + 1023) >> 10;
  int start = tid * per;
  int end = start + per; if (end > n) end = n;
  int sum = 0;
  for (int i = start; i < end && start < n; ++i) sum += counts[i];
  sh[tid] = sum;
  __syncthreads();
  for (int off = 1; off < 1024; off <<= 1) {
    int t = (tid >= off) ? sh[tid - off] : 0;
    __syncthreads();
    if (tid >= off) sh[tid] += t;
    __syncthreads();
  }
  int incl = sh[tid];
  int run = incl - sum;
  for (int i = start; i < end && start < n; ++i) {
    offsets[i] = run; cursor[i] = run; run += counts[i];
  }
  if (tid == 1023) offsets[n] = incl;
}

__global__ __launch_bounds__(256) void k_scatter(const int* __restrict__ ei,
    int* __restrict__ cursor, int* __restrict__ perm, int E)
{
  int e = blockIdx.x * 256 + threadIdx.x;
  if (e < E) {
    int dst = ei[e];
    int pos = atomicAdd(&cursor[dst], 1);
    perm[pos] = e;
  }
}

// ---------------- Node pass: online scatter-softmax + aggregation + Bw ----------------
__global__ __launch_bounds__(256) void k_node(
    const int* __restrict__ ei, const int* __restrict__ offsets,
    const int* __restrict__ perm, const float* __restrict__ conn,
    const float* __restrict__ qkv, const float* __restrict__ Aw,
    const float* __restrict__ Bw, float* __restrict__ No, int N, int E)
{
  const int lane = threadIdx.x & 63;
  int node = blockIdx.x * 4 + (threadIdx.x >> 6);
  node = __builtin_amdgcn_readfirstlane(node);
  if (node >= N) return;

  const float awv = Aw[(lane & 7) * 8 + (lane >> 3)];  // Aw[d, h, 0]
  float bw[8];
#pragma unroll
  for (int dd = 0; dd < 8; ++dd) bw[dd] = Bw[dd * 64 + lane];  // Bw[d, h, c]

  const int beg = offsets[node];
  const int end = offsets[node + 1];
  float m = -INFINITY, l = 0.f, aV = 0.f, aC = 0.f;

  float c_nxt = 0.f, v_nxt = 0.f;
  if (beg < end) {
    int e = perm[beg];
    int src = ei[E + e];
    c_nxt = conn[(size_t)e * 64 + lane];
    v_nxt = qkv[src * 192 + 128 + lane];
  }
  for (int i = beg; i < end; ++i) {
    float c = c_nxt;
    float v = v_nxt;
    if (i + 1 < end) {                     // prefetch next edge before exp chain
      int e2 = perm[i + 1];
      int s2 = ei[E + e2];
      c_nxt = conn[(size_t)e2 * 64 + lane];
      v_nxt = qkv[s2 * 192 + 128 + lane];
    }
    float t = c * awv;
    t += __shfl_xor(t, 1, 64);
    t += __shfl_xor(t, 2, 64);
    t += __shfl_xor(t, 4, 64);
    float s = fminf(fmaxf(t, -5.f), 5.f);
    float mn = fmaxf(m, s);
    float al = __expf(m - mn);
    float wgt = __expf(s - mn);
    l  = l * al + wgt;
    aV = fmaf(wgt, v, aV * al);
    aC = fmaf(wgt, c, aC * al);
    m = mn;
  }

  float inv = 1.f / (l + 1e-16f);
  float rowv = aC * inv;
  float acc = aV * inv;
  const int hbase = lane & 56;
#pragma unroll
  for (int dd = 0; dd < 8; ++dd) {
    float rr = __shfl(rowv, hbase + dd, 64);
    acc = fmaf(rr, bw[dd], acc);
  }
  No[node * 64 + lane] = acc;
}

extern "C" void kernel_launch(void* const* d_in, const int* in_sizes, int n_in,
                              void* d_out, int out_size, void* d_ws, size_t ws_size,
                              hipStream_t stream)
{
  const float* x  = (const float*)d_in[0];
  const float* cf = (const float*)d_in[1];
  const int*   ei = (const int*)d_in[2];
  const float* qw = (const float*)d_in[3];
  const float* qb = (const float*)d_in[4];
  const float* ew = (const float*)d_in[5];
  const float* eb = (const float*)d_in[6];
  const float* Aw = (const float*)d_in[7];
  const float* Bw = (const float*)d_in[8];

  float* No   = (float*)d_out;
  float* conn = (float*)d_out + (size_t)N_NODESC * 64;

  char* ws = (char*)d_ws;
  float* QKV   = (float*)(ws);
  int* counts  = (int*)(ws + 38400000);
  int* offsets = (int*)(ws + 38600000);
  int* cursor  = (int*)(ws + 38800004);
  char* ewb    = ws + 38800016;          // aliases cursor region (safe: see layout note)
  int* perm    = (int*)(ws + 39000004);

  k_zero<<<(N_NODESC + 255) / 256, 256, 0, stream>>>(counts, N_NODESC);
  k_prep<<<4, 256, 0, stream>>>(ew, ewb);
  k_qkv<<<(N_NODESC + 63) / 64, 256, 0, stream>>>(x, qw, qb, QKV, N_NODESC);
  k_edge<<<N_EDGESC / 128, 256, 0, stream>>>(cf, ei, eb, ewb, QKV, conn, counts, N_EDGESC);
  k_scan<<<1, 1024, 0, stream>>>(counts, offsets, cursor, N_NODESC);
  k_scatter<<<(N_EDGESC + 255) / 256, 256, 0, stream>>>(ei, cursor, perm, N_EDGESC);
  k_node<<<N_NODESC / 4, 256, 0, stream>>>(ei, offsets, perm, conn, QKV, Aw, Bw, No, N_NODESC, N_EDGESC);
}

// Round 2
// 759.507 us; speedup vs baseline: 1.0979x; 1.0074x over previous
//
#include <hip/hip_runtime.h>
#include <cstdint>
#include <cmath>

#define N_NODESC 50000
#define N_EDGESC 800000

typedef __bf16 bf16x8 __attribute__((ext_vector_type(8)));
typedef float  f32x4  __attribute__((ext_vector_type(4)));

// ---------------- workspace layout (bytes) ----------------
// QKV    : [0,          38,400,000)   N*192 f32  (Q | K | V per node row)
// counts : [38,400,000, 38,600,000)   N int
// offsets: [38,600,000, 38,800,004)   N+1 int
// cursor : [38,800,004, 39,000,004)   N int
//   ewb  : [38,800,016, 38,832,784)   32 KB prepped bf16 E_weight (hi|lo, swizzled)
//          -- aliases cursor; k_prep writes it before k_edge reads it, and
//          -- k_scan only scribbles cursor AFTER k_edge completes (stream order).
// perm   : [39,000,004, 42,200,004)   E int  (edges sorted by dst)

__global__ __launch_bounds__(256) void k_zero(int* __restrict__ p, int n) {
  int i = blockIdx.x * 256 + threadIdx.x;
  if (i < n) p[i] = 0;
}

// ---------------- prep: E_weight f32 -> split bf16 (hi,lo), XOR-swizzled ----------------
__global__ __launch_bounds__(256) void k_prep(const float* __restrict__ ew,
                                              char* __restrict__ out)
{
  int idx = blockIdx.x * 256 + threadIdx.x;   // [0,1024)
  int j = idx >> 3;
  int c = idx & 7;
  float4 a = *(const float4*)&ew[j * 64 + c * 8];
  float4 b = *(const float4*)&ew[j * 64 + c * 8 + 4];
  float f[8] = {a.x, a.y, a.z, a.w, b.x, b.y, b.z, b.w};
  bf16x8 hv, lv;
#pragma unroll
  for (int i = 0; i < 8; ++i) {
    float fv = f[i];
    __bf16 h = (__bf16)fv;                    // RN to bf16
    hv[i] = h;
    lv[i] = (__bf16)(fv - (float)h);          // residual, RN to bf16
  }
  int swz = c ^ (j & 7);
  *(bf16x8*)(out + j * 128 + swz * 16) = hv;
  *(bf16x8*)(out + 16384 + j * 128 + swz * 16) = lv;
}

// ---------------- QKV = x @ Wqkv^T + b  (N x 192) ----------------
__global__ __launch_bounds__(256) void k_qkv(
    const float* __restrict__ x, const float* __restrict__ w,
    const float* __restrict__ bias, float* __restrict__ qkv, int N)
{
  __shared__ float wT[32 * 193];
  __shared__ float xT[32 * 65];
  const int tid = threadIdx.x;
  const int node0 = blockIdx.x * 64;
  const int tn = tid & 15;
  const int tj = tid >> 4;

  float acc[4][12];
#pragma unroll
  for (int i = 0; i < 4; ++i)
#pragma unroll
    for (int p = 0; p < 12; ++p) acc[i][p] = 0.f;

  for (int kh = 0; kh < 2; ++kh) {
#pragma unroll
    for (int it = 0; it < 6; ++it) {
      int idx4 = tid + it * 256;
      int j = idx4 >> 3;
      int k4 = idx4 & 7;
      float4 a = *(const float4*)&w[j * 64 + kh * 32 + k4 * 4];
      wT[(k4 * 4 + 0) * 193 + j] = a.x;
      wT[(k4 * 4 + 1) * 193 + j] = a.y;
      wT[(k4 * 4 + 2) * 193 + j] = a.z;
      wT[(k4 * 4 + 3) * 193 + j] = a.w;
    }
#pragma unroll
    for (int it = 0; it < 2; ++it) {
      int idx4 = tid + it * 256;
      int n = idx4 >> 3;
      int k4 = idx4 & 7;
      int gn = node0 + n;
      float4 a = make_float4(0.f, 0.f, 0.f, 0.f);
      if (gn < N) a = *(const float4*)&x[gn * 64 + kh * 32 + k4 * 4];
      xT[(k4 * 4 + 0) * 65 + n] = a.x;
      xT[(k4 * 4 + 1) * 65 + n] = a.y;
      xT[(k4 * 4 + 2) * 65 + n] = a.z;
      xT[(k4 * 4 + 3) * 65 + n] = a.w;
    }
    __syncthreads();
#pragma unroll 8
    for (int k = 0; k < 32; ++k) {
      float xa[4], wa[12];
#pragma unroll
      for (int i = 0; i < 4; ++i) xa[i] = xT[k * 65 + tn * 4 + i];
#pragma unroll
      for (int p = 0; p < 12; ++p) wa[p] = wT[k * 193 + tj * 12 + p];
#pragma unroll
      for (int i = 0; i < 4; ++i)
#pragma unroll
        for (int p = 0; p < 12; ++p)
          acc[i][p] = fmaf(xa[i], wa[p], acc[i][p]);
    }
    __syncthreads();
  }

  float b[12];
#pragma unroll
  for (int p = 0; p < 12; ++p) b[p] = bias[tj * 12 + p];
#pragma unroll
  for (int i = 0; i < 4; ++i) {
    int gn = node0 + tn * 4 + i;
    if (gn < N) {
      float* o = &qkv[gn * 192 + tj * 12];
#pragma unroll
      for (int p = 0; p < 12; ++p) o[p] = acc[i][p] + b[p];
    }
  }
}

// ---------------- Edge pass: MFMA split-bf16 GEMM (E x 64) @ (64 x 128) + fused epilogue
// Block: 128 edges, 4 waves x 32 edges (2 A-tiles of 16). K=64 = 2 MFMA steps.
// ALL loads (B copy, A rows, edge indices, Q/K gathers) are issued BEFORE the
// barrier; the barrier's vmcnt(0) drain absorbs the full gather latency once,
// concurrently, instead of 8 serialized L3 round-trips inside the epilogue.
// D layout (measured, m89/m91): col=lane&15, row=(lane>>4)*4+reg.
__global__ __launch_bounds__(256) void k_edge(
    const float* __restrict__ cf, const int* __restrict__ ei,
    const float* __restrict__ ebias, const char* __restrict__ ewb,
    const float* __restrict__ qkv, float* __restrict__ conn_out,
    int* __restrict__ counts, int E)
{
  __shared__ uint4 Bsh4[2048];              // 32 KB: hi [0,16K), lo [16K,32K)
  char* Bsh = (char*)Bsh4;
  const int tid  = threadIdx.x;
  const int lane = tid & 63;
  const int lr   = lane & 15;               // A row / B col / D col
  const int lg   = lane >> 4;               // k-group / D row-group
  const int wave = tid >> 6;
  const int e0   = blockIdx.x * 128 + wave * 32;

  // --- phase 0a: edge indices first (L2-fast; heads of the gather dep chain)
  int dstv[8], srcv[8];
#pragma unroll
  for (int tr = 0; tr < 8; ++tr) {
    const int e = e0 + (tr >> 2) * 16 + lg * 4 + (tr & 3);
    dstv[tr] = ei[e];
    srcv[tr] = ei[E + e];
  }

  // --- phase 0b: B copy loads (ws slab, L2-resident)
  uint4 breg[8];
#pragma unroll
  for (int it = 0; it < 8; ++it)
    breg[it] = *(const uint4*)(ewb + tid * 16 + it * 4096);

  // --- phase 0c: A tiles: 2 tiles x 2 K-steps x 8 consecutive f32 per lane
  float af[2][2][8];
#pragma unroll
  for (int t = 0; t < 2; ++t)
#pragma unroll
    for (int s = 0; s < 2; ++s) {
      const float* p = &cf[(size_t)(e0 + t * 16 + lr) * 64 + s * 32 + lg * 8];
      float4 x0 = *(const float4*)p;
      float4 x1 = *(const float4*)(p + 4);
      af[t][s][0] = x0.x; af[t][s][1] = x0.y; af[t][s][2] = x0.z; af[t][s][3] = x0.w;
      af[t][s][4] = x1.x; af[t][s][5] = x1.y; af[t][s][6] = x1.z; af[t][s][7] = x1.w;
    }

  // --- phase 1: Q/K gathers, issued long before their epilogue use
  float qv[8][4], kv[8][4];
#pragma unroll
  for (int tr = 0; tr < 8; ++tr) {
    const float* qrow = &qkv[(size_t)dstv[tr] * 192];
    const float* krow = &qkv[(size_t)srcv[tr] * 192 + 64];
#pragma unroll
    for (int c = 0; c < 4; ++c) {
      qv[tr][c] = qrow[c * 16 + lr];
      kv[tr][c] = krow[c * 16 + lr];
    }
  }

  // --- phase 2: B regs -> LDS (identity copy; lanes 16B apart: conflict-free)
#pragma unroll
  for (int it = 0; it < 8; ++it)
    *(uint4*)(Bsh + tid * 16 + it * 4096) = breg[it];

  // --- phase 3: convert A to hi/lo bf16 fragments
  bf16x8 ah[2][2], al[2][2];
#pragma unroll
  for (int t = 0; t < 2; ++t)
#pragma unroll
    for (int s = 0; s < 2; ++s)
#pragma unroll
      for (int i = 0; i < 8; ++i) {
        float fv = af[t][s][i];
        __bf16 h = (__bf16)fv;
        ah[t][s][i] = h;
        al[t][s][i] = (__bf16)(fv - (float)h);
      }

  __syncthreads();   // drains vmcnt(0): A, B, and gathers all land here

  // --- fold gathers to halve live registers through the MFMA phase
  float qk[8][4];
#pragma unroll
  for (int tr = 0; tr < 8; ++tr)
#pragma unroll
    for (int c = 0; c < 4; ++c)
      qk[tr][c] = qv[tr][c] + kv[tr][c];

  f32x4 acc[2][8];
#pragma unroll
  for (int t = 0; t < 2; ++t)
#pragma unroll
    for (int ct = 0; ct < 8; ++ct)
      acc[t][ct] = (f32x4){0.f, 0.f, 0.f, 0.f};

  // --- MFMA main: per (s,ct): 2 ds_read_b128, 6 MFMAs (reused over 2 A-tiles)
#pragma unroll
  for (int s = 0; s < 2; ++s) {
    const int swz = ((s * 4 + lg) ^ (lr & 7)) * 16;   // (j&7)==(lr&7) since ct*16%8==0
#pragma unroll
    for (int ct = 0; ct < 8; ++ct) {
      const int j = ct * 16 + lr;
      const bf16x8 bh = *(const bf16x8*)(Bsh + j * 128 + swz);
      const bf16x8 bl = *(const bf16x8*)(Bsh + 16384 + j * 128 + swz);
#pragma unroll
      for (int t = 0; t < 2; ++t) {
        acc[t][ct] = __builtin_amdgcn_mfma_f32_16x16x32_bf16(ah[t][s], bh, acc[t][ct], 0, 0, 0);
        acc[t][ct] = __builtin_amdgcn_mfma_f32_16x16x32_bf16(al[t][s], bh, acc[t][ct], 0, 0, 0);
        acc[t][ct] = __builtin_amdgcn_mfma_f32_16x16x32_bf16(ah[t][s], bl, acc[t][ct], 0, 0, 0);
      }
    }
  }

  // --- fused epilogue: conn = relu(sign_sqrt((Q[dst]+K[src])*Ew) + Eb)
  float be[4], bb[4];
#pragma unroll
  for (int ct = 0; ct < 4; ++ct) {
    be[ct] = ebias[ct * 16 + lr];
    bb[ct] = ebias[64 + ct * 16 + lr];
  }

#pragma unroll
  for (int tr = 0; tr < 8; ++tr) {
    const int t = tr >> 2;
    const int r = tr & 3;
    const int e = e0 + t * 16 + lg * 4 + r;           // D row -> edge
    float* orow = &conn_out[(size_t)e * 64];
#pragma unroll
    for (int ct = 0; ct < 4; ++ct) {
      float aE = acc[t][ct][r]     + be[ct];
      float aB = acc[t][ct + 4][r] + bb[ct];
      float sv = qk[tr][ct] * aE;
      float rt = sqrtf(fabsf(sv));
      float c2 = (sv >= 0.f) ? rt : -rt;              // sqrt_relu(x)-sqrt_relu(-x)
      orow[ct * 16 + lr] = fmaxf(c2 + aB, 0.f);
    }
    if (lr == 0) atomicAdd(&counts[dstv[tr]], 1);
  }
}

// ---------------- single-block exclusive scan (CSR offsets + cursor) ----------------
__global__ void k_scan(const int* __restrict__ counts, int* __restrict__ offsets,
                       int* __restrict__ cursor, int n)
{
  __shared__ int sh[1024];
  const int tid = threadIdx.x;
  const int per = (n + 1023) >> 10;
  int start = tid * per;
  int end = start + per; if (end > n) end = n;
  int sum = 0;
  for (int i = start; i < end && start < n; ++i) sum += counts[i];
  sh[tid] = sum;
  __syncthreads();
  for (int off = 1; off < 1024; off <<= 1) {
    int t = (tid >= off) ? sh[tid - off] : 0;
    __syncthreads();
    if (tid >= off) sh[tid] += t;
    __syncthreads();
  }
  int incl = sh[tid];
  int run = incl - sum;
  for (int i = start; i < end && start < n; ++i) {
    offsets[i] = run; cursor[i] = run; run += counts[i];
  }
  if (tid == 1023) offsets[n] = incl;
}

__global__ __launch_bounds__(256) void k_scatter(const int* __restrict__ ei,
    int* __restrict__ cursor, int* __restrict__ perm, int E)
{
  int e = blockIdx.x * 256 + threadIdx.x;
  if (e < E) {
    int dst = ei[e];
    int pos = atomicAdd(&cursor[dst], 1);
    perm[pos] = e;
  }
}

// ---------------- Node pass: online scatter-softmax + aggregation + Bw ----------------
// One wave per node; lane = h*8+d. Depth-2 software prefetch of conn/V rows:
// the conn gathers are random 256B rows of a 205 MB array (pure HBM latency),
// depth-1 covered <10% of the ~900cy round trip.
__global__ __launch_bounds__(256) void k_node(
    const int* __restrict__ ei, const int* __restrict__ offsets,
    const int* __restrict__ perm, const float* __restrict__ conn,
    const float* __restrict__ qkv, const float* __restrict__ Aw,
    const float* __restrict__ Bw, float* __restrict__ No, int N, int E)
{
  const int lane = threadIdx.x & 63;
  int node = blockIdx.x * 4 + (threadIdx.x >> 6);
  node = __builtin_amdgcn_readfirstlane(node);
  if (node >= N) return;

  const float awv = Aw[(lane & 7) * 8 + (lane >> 3)];  // Aw[d, h, 0]
  float bw[8];
#pragma unroll
  for (int dd = 0; dd < 8; ++dd) bw[dd] = Bw[dd * 64 + lane];  // Bw[d, h, c]

  const int beg = offsets[node];
  const int end = offsets[node + 1];
  float m = -INFINITY, l = 0.f, aV = 0.f, aC = 0.f;

  float c0 = 0.f, v0 = 0.f, c1 = 0.f, v1 = 0.f;
  if (beg < end) {
    int e = perm[beg];
    int s = ei[E + e];
    c0 = conn[(size_t)e * 64 + lane];
    v0 = qkv[s * 192 + 128 + lane];
  }
  if (beg + 1 < end) {
    int e = perm[beg + 1];
    int s = ei[E + e];
    c1 = conn[(size_t)e * 64 + lane];
    v1 = qkv[s * 192 + 128 + lane];
  }
  for (int i = beg; i < end; ++i) {
    float c = c0, v = v0;
    c0 = c1; v0 = v1;
    if (i + 2 < end) {                     // prefetch 2 ahead of the exp chain
      int e2 = perm[i + 2];
      int s2 = ei[E + e2];
      c1 = conn[(size_t)e2 * 64 + lane];
      v1 = qkv[s2 * 192 + 128 + lane];
    }
    float t = c * awv;
    t += __shfl_xor(t, 1, 64);
    t += __shfl_xor(t, 2, 64);
    t += __shfl_xor(t, 4, 64);
    float s = fminf(fmaxf(t, -5.f), 5.f);
    float mn = fmaxf(m, s);
    float al = __expf(m - mn);
    float wgt = __expf(s - mn);
    l  = l * al + wgt;
    aV = fmaf(wgt, v, aV * al);
    aC = fmaf(wgt, c, aC * al);
    m = mn;
  }

  float inv = 1.f / (l + 1e-16f);
  float rowv = aC * inv;
  float acc = aV * inv;
  const int hbase = lane & 56;
#pragma unroll
  for (int dd = 0; dd < 8; ++dd) {
    float rr = __shfl(rowv, hbase + dd, 64);
    acc = fmaf(rr, bw[dd], acc);
  }
  No[node * 64 + lane] = acc;
}

extern "C" void kernel_launch(void* const* d_in, const int* in_sizes, int n_in,
                              void* d_out, int out_size, void* d_ws, size_t ws_size,
                              hipStream_t stream)
{
  const float* x  = (const float*)d_in[0];
  const float* cf = (const float*)d_in[1];
  const int*   ei = (const int*)d_in[2];
  const float* qw = (const float*)d_in[3];
  const float* qb = (const float*)d_in[4];
  const float* ew = (const float*)d_in[5];
  const float* eb = (const float*)d_in[6];
  const float* Aw = (const float*)d_in[7];
  const float* Bw = (const float*)d_in[8];

  float* No   = (float*)d_out;
  float* conn = (float*)d_out + (size_t)N_NODESC * 64;

  char* ws = (char*)d_ws;
  float* QKV   = (float*)(ws);
  int* counts  = (int*)(ws + 38400000);
  int* offsets = (int*)(ws + 38600000);
  int* cursor  = (int*)(ws + 38800004);
  char* ewb    = ws + 38800016;          // aliases cursor region (safe: see layout note)
  int* perm    = (int*)(ws + 39000004);

  k_zero<<<(N_NODESC + 255) / 256, 256, 0, stream>>>(counts, N_NODESC);
  k_prep<<<4, 256, 0, stream>>>(ew, ewb);
  k_qkv<<<(N_NODESC + 63) / 64, 256, 0, stream>>>(x, qw, qb, QKV, N_NODESC);
  k_edge<<<N_EDGESC / 128, 256, 0, stream>>>(cf, ei, eb, ewb, QKV, conn, counts, N_EDGESC);
  k_scan<<<1, 1024, 0, stream>>>(counts, offsets, cursor, N_NODESC);
  k_scatter<<<(N_EDGESC + 255) / 256, 256, 0, stream>>>(ei, cursor, perm, N_EDGESC);
  k_node<<<N_NODESC / 4, 256, 0, stream>>>(ei, offsets, perm, conn, QKV, Aw, Bw, No, N_NODESC, N_EDGESC);
}

// Round 3
// 728.899 us; speedup vs baseline: 1.1441x; 1.0420x over previous
//
#include <hip/hip_runtime.h>
#include <cstdint>
#include <cmath>

#define N_NODESC 50000
#define N_EDGESC 800000

typedef __bf16 bf16x8 __attribute__((ext_vector_type(8)));
typedef float  f32x4  __attribute__((ext_vector_type(4)));

// ---------------- workspace layout (bytes) ----------------
// QKV    : [0,          38,400,000)   N*192 f32  (Q | K | V per node row)
// counts : [38,400,000, 38,600,000)   N int
// offsets: [38,600,000, 38,800,004)   N+1 int
// cursor : [38,800,004, 39,000,004)   N int
//   ewb  : [38,800,016, 38,832,784)   32 KB prepped bf16 E_weight (hi|lo, swizzled)
//          -- aliases cursor; k_prep writes it before k_edge reads it, and
//          -- k_scan only scribbles cursor AFTER k_edge completes (stream order).
// perm   : [39,000,004, 42,200,004)   E int  (edges sorted by dst)

__global__ __launch_bounds__(256) void k_zero(int* __restrict__ p, int n) {
  int i = blockIdx.x * 256 + threadIdx.x;
  if (i < n) p[i] = 0;
}

// ---------------- prep: E_weight f32 -> split bf16 (hi,lo), XOR-swizzled ----------------
// Tile-column j holds FEATURE f(j) = half*64 + (j&15)*4 + ((j&63)>>4), so that in the
// MFMA D-layout (col = ct*16+lr) lane lr owns 4 CONSECUTIVE features lr*4..lr*4+3.
// This makes the k_edge epilogue's Q/K gathers and conn stores float4 (256B/16-lane
// segments) instead of 64 scalar loads + 32 scalar stores per thread.
__global__ __launch_bounds__(256) void k_prep(const float* __restrict__ ew,
                                              char* __restrict__ out)
{
  int idx = blockIdx.x * 256 + threadIdx.x;   // [0,1024)
  int j = idx >> 3;                           // tile-col [0,128)
  int c = idx & 7;                            // k-chunk of 8
  int jl = j & 63;
  int f = (j & 64) + (jl & 15) * 4 + (jl >> 4);   // feature row of ew
  float4 a = *(const float4*)&ew[f * 64 + c * 8];
  float4 b = *(const float4*)&ew[f * 64 + c * 8 + 4];
  float fv8[8] = {a.x, a.y, a.z, a.w, b.x, b.y, b.z, b.w};
  bf16x8 hv, lv;
#pragma unroll
  for (int i = 0; i < 8; ++i) {
    float fv = fv8[i];
    __bf16 h = (__bf16)fv;                    // RN to bf16
    hv[i] = h;
    lv[i] = (__bf16)(fv - (float)h);          // residual, RN to bf16
  }
  int swz = c ^ (j & 7);
  *(bf16x8*)(out + j * 128 + swz * 16) = hv;
  *(bf16x8*)(out + 16384 + j * 128 + swz * 16) = lv;
}

// ---------------- QKV = x @ Wqkv^T + b  (N x 192) ----------------
__global__ __launch_bounds__(256) void k_qkv(
    const float* __restrict__ x, const float* __restrict__ w,
    const float* __restrict__ bias, float* __restrict__ qkv, int N)
{
  __shared__ float wT[32 * 193];
  __shared__ float xT[32 * 65];
  const int tid = threadIdx.x;
  const int node0 = blockIdx.x * 64;
  const int tn = tid & 15;
  const int tj = tid >> 4;

  float acc[4][12];
#pragma unroll
  for (int i = 0; i < 4; ++i)
#pragma unroll
    for (int p = 0; p < 12; ++p) acc[i][p] = 0.f;

  for (int kh = 0; kh < 2; ++kh) {
#pragma unroll
    for (int it = 0; it < 6; ++it) {
      int idx4 = tid + it * 256;
      int j = idx4 >> 3;
      int k4 = idx4 & 7;
      float4 a = *(const float4*)&w[j * 64 + kh * 32 + k4 * 4];
      wT[(k4 * 4 + 0) * 193 + j] = a.x;
      wT[(k4 * 4 + 1) * 193 + j] = a.y;
      wT[(k4 * 4 + 2) * 193 + j] = a.z;
      wT[(k4 * 4 + 3) * 193 + j] = a.w;
    }
#pragma unroll
    for (int it = 0; it < 2; ++it) {
      int idx4 = tid + it * 256;
      int n = idx4 >> 3;
      int k4 = idx4 & 7;
      int gn = node0 + n;
      float4 a = make_float4(0.f, 0.f, 0.f, 0.f);
      if (gn < N) a = *(const float4*)&x[gn * 64 + kh * 32 + k4 * 4];
      xT[(k4 * 4 + 0) * 65 + n] = a.x;
      xT[(k4 * 4 + 1) * 65 + n] = a.y;
      xT[(k4 * 4 + 2) * 65 + n] = a.z;
      xT[(k4 * 4 + 3) * 65 + n] = a.w;
    }
    __syncthreads();
#pragma unroll 8
    for (int k = 0; k < 32; ++k) {
      float xa[4], wa[12];
#pragma unroll
      for (int i = 0; i < 4; ++i) xa[i] = xT[k * 65 + tn * 4 + i];
#pragma unroll
      for (int p = 0; p < 12; ++p) wa[p] = wT[k * 193 + tj * 12 + p];
#pragma unroll
      for (int i = 0; i < 4; ++i)
#pragma unroll
        for (int p = 0; p < 12; ++p)
          acc[i][p] = fmaf(xa[i], wa[p], acc[i][p]);
    }
    __syncthreads();
  }

  float b[12];
#pragma unroll
  for (int p = 0; p < 12; ++p) b[p] = bias[tj * 12 + p];
#pragma unroll
  for (int i = 0; i < 4; ++i) {
    int gn = node0 + tn * 4 + i;
    if (gn < N) {
      float* o = &qkv[gn * 192 + tj * 12];
#pragma unroll
      for (int p = 0; p < 12; ++p) o[p] = acc[i][p] + b[p];
    }
  }
}

// ---------------- Edge pass: MFMA split-bf16 GEMM (E x 64) @ (64 x 128) + fused epilogue
// Block: 128 edges, 4 waves x 32 edges (2 A-tiles of 16). K=64 = 2 MFMA steps.
// ALL loads (ei, B copy, A rows, Q/K float4 gathers) issue BEFORE the barrier;
// its vmcnt(0) drain absorbs the gather latency once, concurrently.
// Feature permutation (see k_prep) makes every epilogue access float4.
__global__ __launch_bounds__(256) void k_edge(
    const float* __restrict__ cf, const int* __restrict__ ei,
    const float* __restrict__ ebias, const char* __restrict__ ewb,
    const float* __restrict__ qkv, float* __restrict__ conn_out,
    int* __restrict__ counts, int E)
{
  __shared__ uint4 Bsh4[2048];              // 32 KB: hi [0,16K), lo [16K,32K)
  char* Bsh = (char*)Bsh4;
  const int tid  = threadIdx.x;
  const int lane = tid & 63;
  const int lr   = lane & 15;               // A row / B col / D col
  const int lg   = lane >> 4;               // k-group / D row-group
  const int wave = tid >> 6;
  const int e0   = blockIdx.x * 128 + wave * 32;

  // --- phase 0a: edge indices first (heads of the gather dep chain)
  int dstv[8], srcv[8];
#pragma unroll
  for (int tr = 0; tr < 8; ++tr) {
    const int e = e0 + (tr >> 2) * 16 + lg * 4 + (tr & 3);
    dstv[tr] = ei[e];
    srcv[tr] = ei[E + e];
  }

  // --- phase 0b: B copy loads (ws slab, L2-resident)
  uint4 breg[8];
#pragma unroll
  for (int it = 0; it < 8; ++it)
    breg[it] = *(const uint4*)(ewb + tid * 16 + it * 4096);

  // --- phase 0c: A tiles: 2 tiles x 2 K-steps x 8 consecutive f32 per lane
  float af[2][2][8];
#pragma unroll
  for (int t = 0; t < 2; ++t)
#pragma unroll
    for (int s = 0; s < 2; ++s) {
      const float* p = &cf[(size_t)(e0 + t * 16 + lr) * 64 + s * 32 + lg * 8];
      float4 x0 = *(const float4*)p;
      float4 x1 = *(const float4*)(p + 4);
      af[t][s][0] = x0.x; af[t][s][1] = x0.y; af[t][s][2] = x0.z; af[t][s][3] = x0.w;
      af[t][s][4] = x1.x; af[t][s][5] = x1.y; af[t][s][6] = x1.z; af[t][s][7] = x1.w;
    }

  // --- phase 1: Q/K float4 gathers (lane lr owns features lr*4..lr*4+3)
  float4 qv4[8], kv4[8];
#pragma unroll
  for (int tr = 0; tr < 8; ++tr) {
    qv4[tr] = *(const float4*)&qkv[(size_t)dstv[tr] * 192 + lr * 4];
    kv4[tr] = *(const float4*)&qkv[(size_t)srcv[tr] * 192 + 64 + lr * 4];
  }

  // --- phase 2: B regs -> LDS (identity copy; lanes 16B apart: conflict-free)
#pragma unroll
  for (int it = 0; it < 8; ++it)
    *(uint4*)(Bsh + tid * 16 + it * 4096) = breg[it];

  // --- phase 3: convert A to hi/lo bf16 fragments
  bf16x8 ah[2][2], al[2][2];
#pragma unroll
  for (int t = 0; t < 2; ++t)
#pragma unroll
    for (int s = 0; s < 2; ++s)
#pragma unroll
      for (int i = 0; i < 8; ++i) {
        float fv = af[t][s][i];
        __bf16 h = (__bf16)fv;
        ah[t][s][i] = h;
        al[t][s][i] = (__bf16)(fv - (float)h);
      }

  __syncthreads();   // drains vmcnt(0): A, B, and gathers all land here

  // --- fold gathers to halve live registers through the MFMA phase
  float qk[8][4];
#pragma unroll
  for (int tr = 0; tr < 8; ++tr) {
    qk[tr][0] = qv4[tr].x + kv4[tr].x;
    qk[tr][1] = qv4[tr].y + kv4[tr].y;
    qk[tr][2] = qv4[tr].z + kv4[tr].z;
    qk[tr][3] = qv4[tr].w + kv4[tr].w;
  }

  f32x4 acc[2][8];
#pragma unroll
  for (int t = 0; t < 2; ++t)
#pragma unroll
    for (int ct = 0; ct < 8; ++ct)
      acc[t][ct] = (f32x4){0.f, 0.f, 0.f, 0.f};

  // --- MFMA main: per (s,ct): 2 ds_read_b128, 6 MFMAs (reused over 2 A-tiles)
#pragma unroll
  for (int s = 0; s < 2; ++s) {
    const int swz = ((s * 4 + lg) ^ (lr & 7)) * 16;   // (j&7)==(lr&7) since ct*16%8==0
#pragma unroll
    for (int ct = 0; ct < 8; ++ct) {
      const int j = ct * 16 + lr;
      const bf16x8 bh = *(const bf16x8*)(Bsh + j * 128 + swz);
      const bf16x8 bl = *(const bf16x8*)(Bsh + 16384 + j * 128 + swz);
#pragma unroll
      for (int t = 0; t < 2; ++t) {
        acc[t][ct] = __builtin_amdgcn_mfma_f32_16x16x32_bf16(ah[t][s], bh, acc[t][ct], 0, 0, 0);
        acc[t][ct] = __builtin_amdgcn_mfma_f32_16x16x32_bf16(al[t][s], bh, acc[t][ct], 0, 0, 0);
        acc[t][ct] = __builtin_amdgcn_mfma_f32_16x16x32_bf16(ah[t][s], bl, acc[t][ct], 0, 0, 0);
      }
    }
  }

  // --- fused epilogue: conn = relu(sign_sqrt((Q[dst]+K[src])*Ew) + Eb)
  // acc[t][ct][r] (ct<4) is feature lr*4+ct of Ew-half; ct+4 is Eb-half.
  float be[4], bb[4];
  {
    float4 bev = *(const float4*)&ebias[lr * 4];
    float4 bbv = *(const float4*)&ebias[64 + lr * 4];
    be[0] = bev.x; be[1] = bev.y; be[2] = bev.z; be[3] = bev.w;
    bb[0] = bbv.x; bb[1] = bbv.y; bb[2] = bbv.z; bb[3] = bbv.w;
  }

#pragma unroll
  for (int tr = 0; tr < 8; ++tr) {
    const int t = tr >> 2;
    const int r = tr & 3;
    const int e = e0 + t * 16 + lg * 4 + r;           // D row -> edge
    float ov[4];
#pragma unroll
    for (int ct = 0; ct < 4; ++ct) {
      float aE = acc[t][ct][r]     + be[ct];
      float aB = acc[t][ct + 4][r] + bb[ct];
      float sv = qk[tr][ct] * aE;
      float rt = sqrtf(fabsf(sv));
      float c2 = (sv >= 0.f) ? rt : -rt;              // sqrt_relu(x)-sqrt_relu(-x)
      ov[ct] = fmaxf(c2 + aB, 0.f);
    }
    float4 o = make_float4(ov[0], ov[1], ov[2], ov[3]);
    *(float4*)&conn_out[(size_t)e * 64 + lr * 4] = o;
    if (lr == 0) atomicAdd(&counts[dstv[tr]], 1);
  }
}

// ---------------- single-block exclusive scan (CSR offsets + cursor) ----------------
__global__ void k_scan(const int* __restrict__ counts, int* __restrict__ offsets,
                       int* __restrict__ cursor, int n)
{
  __shared__ int sh[1024];
  const int tid = threadIdx.x;
  const int per = (n + 1023) >> 10;
  int start = tid * per;
  int end = start + per; if (end > n) end = n;
  int sum = 0;
  for (int i = start; i < end && start < n; ++i) sum += counts[i];
  sh[tid] = sum;
  __syncthreads();
  for (int off = 1; off < 1024; off <<= 1) {
    int t = (tid >= off) ? sh[tid - off] : 0;
    __syncthreads();
    if (tid >= off) sh[tid] += t;
    __syncthreads();
  }
  int incl = sh[tid];
  int run = incl - sum;
  for (int i = start; i < end && start < n; ++i) {
    offsets[i] = run; cursor[i] = run; run += counts[i];
  }
  if (tid == 1023) offsets[n] = incl;
}

__global__ __launch_bounds__(256) void k_scatter(const int* __restrict__ ei,
    int* __restrict__ cursor, int* __restrict__ perm, int E)
{
  int e = blockIdx.x * 256 + threadIdx.x;
  if (e < E) {
    int dst = ei[e];
    int pos = atomicAdd(&cursor[dst], 1);
    perm[pos] = e;
  }
}

// ---------------- Node pass: scatter-softmax + aggregation + Bw ----------------
// One wave per node; lane = h*8+d. Scores are clamped to [-5,5] BEFORE softmax,
// so exp(s) <= 148.4 and no online max-tracking is needed: the per-edge serial
// chain is just exp -> fma. Depth-1 prefetch (depth-2 measured as a regression).
__global__ __launch_bounds__(256) void k_node(
    const int* __restrict__ ei, const int* __restrict__ offsets,
    const int* __restrict__ perm, const float* __restrict__ conn,
    const float* __restrict__ qkv, const float* __restrict__ Aw,
    const float* __restrict__ Bw, float* __restrict__ No, int N, int E)
{
  const int lane = threadIdx.x & 63;
  int node = blockIdx.x * 4 + (threadIdx.x >> 6);
  node = __builtin_amdgcn_readfirstlane(node);
  if (node >= N) return;

  const float awv = Aw[(lane & 7) * 8 + (lane >> 3)];  // Aw[d, h, 0]
  float bw[8];
#pragma unroll
  for (int dd = 0; dd < 8; ++dd) bw[dd] = Bw[dd * 64 + lane];  // Bw[d, h, c]

  const int beg = offsets[node];
  const int end = offsets[node + 1];
  float l = 0.f, aV = 0.f, aC = 0.f;

  float c_nxt = 0.f, v_nxt = 0.f;
  if (beg < end) {
    int e = perm[beg];
    int src = ei[E + e];
    c_nxt = conn[(size_t)e * 64 + lane];
    v_nxt = qkv[src * 192 + 128 + lane];
  }
  for (int i = beg; i < end; ++i) {
    float c = c_nxt;
    float v = v_nxt;
    if (i + 1 < end) {                     // prefetch next edge before exp chain
      int e2 = perm[i + 1];
      int s2 = ei[E + e2];
      c_nxt = conn[(size_t)e2 * 64 + lane];
      v_nxt = qkv[s2 * 192 + 128 + lane];
    }
    float t = c * awv;
    t += __shfl_xor(t, 1, 64);
    t += __shfl_xor(t, 2, 64);
    t += __shfl_xor(t, 4, 64);
    float s = fminf(fmaxf(t, -5.f), 5.f);
    float wgt = __expf(s);                 // bounded: exp(5)=148.4, no max needed
    l += wgt;
    aV = fmaf(wgt, v, aV);
    aC = fmaf(wgt, c, aC);
  }

  float inv = 1.f / (l + 1e-16f);
  float rowv = aC * inv;
  float acc = aV * inv;
  const int hbase = lane & 56;
#pragma unroll
  for (int dd = 0; dd < 8; ++dd) {
    float rr = __shfl(rowv, hbase + dd, 64);
    acc = fmaf(rr, bw[dd], acc);
  }
  No[node * 64 + lane] = acc;
}

extern "C" void kernel_launch(void* const* d_in, const int* in_sizes, int n_in,
                              void* d_out, int out_size, void* d_ws, size_t ws_size,
                              hipStream_t stream)
{
  const float* x  = (const float*)d_in[0];
  const float* cf = (const float*)d_in[1];
  const int*   ei = (const int*)d_in[2];
  const float* qw = (const float*)d_in[3];
  const float* qb = (const float*)d_in[4];
  const float* ew = (const float*)d_in[5];
  const float* eb = (const float*)d_in[6];
  const float* Aw = (const float*)d_in[7];
  const float* Bw = (const float*)d_in[8];

  float* No   = (float*)d_out;
  float* conn = (float*)d_out + (size_t)N_NODESC * 64;

  char* ws = (char*)d_ws;
  float* QKV   = (float*)(ws);
  int* counts  = (int*)(ws + 38400000);
  int* offsets = (int*)(ws + 38600000);
  int* cursor  = (int*)(ws + 38800004);
  char* ewb    = ws + 38800016;          // aliases cursor region (safe: see layout note)
  int* perm    = (int*)(ws + 39000004);

  k_zero<<<(N_NODESC + 255) / 256, 256, 0, stream>>>(counts, N_NODESC);
  k_prep<<<4, 256, 0, stream>>>(ew, ewb);
  k_qkv<<<(N_NODESC + 63) / 64, 256, 0, stream>>>(x, qw, qb, QKV, N_NODESC);
  k_edge<<<N_EDGESC / 128, 256, 0, stream>>>(cf, ei, eb, ewb, QKV, conn, counts, N_EDGESC);
  k_scan<<<1, 1024, 0, stream>>>(counts, offsets, cursor, N_NODESC);
  k_scatter<<<(N_EDGESC + 255) / 256, 256, 0, stream>>>(ei, cursor, perm, N_EDGESC);
  k_node<<<N_NODESC / 4, 256, 0, stream>>>(ei, offsets, perm, conn, QKV, Aw, Bw, No, N_NODESC, N_EDGESC);
}